// Round 9
// baseline (1716.949 us; speedup 1.0000x reference)
//
#include <hip/hip_runtime.h>
#include <stdint.h>

#define BATCH   8192
#define IN_DIM  256
#define HID_DIM 16384
#define OUT_DIM 256

#define SELCAPF 2048
#define TKCAP   2048

typedef __attribute__((ext_vector_type(4))) float f32x4;
typedef __attribute__((ext_vector_type(2))) float f32x2;

__device__ __forceinline__ void load_lds_16B(const void* g, void* l) {
  __builtin_amdgcn_global_load_lds(
      (const __attribute__((address_space(1))) unsigned int*)g,
      (__attribute__((address_space(3))) unsigned int*)l, 16, 0, 0);
}
__device__ __forceinline__ float bf16u_to_f(unsigned short u) {
  return __uint_as_float(((unsigned)u) << 16);
}
__device__ __forceinline__ unsigned short f_to_bf16_rne(float f) {
  unsigned u = __float_as_uint(f);
  u += 0x7fffu + ((u >> 16) & 1u);
  return (unsigned short)(u >> 16);
}
__device__ __forceinline__ int read_k(const int* kptr) {
  int k = kptr[0];
  if (k <= 0 || k > 100000000) {
    float kf = __int_as_float(k);
    if (kf >= 1.f && kf <= 16384.f) k = (int)kf;
  }
  if (k < 1) k = 1;
  if (k > HID_DIM) k = HID_DIM;
  return k;
}
__device__ __forceinline__ f32x2 fma2(f32x2 a, f32x2 b, f32x2 c) {
#if __has_builtin(__builtin_elementwise_fma)
  return __builtin_elementwise_fma(a, b, c);   // v_pk_fma_f32: two independent IEEE FMAs
#else
  f32x2 r; r[0] = fmaf(a[0], b[0], c[0]); r[1] = fmaf(a[1], b[1], c[1]); return r;
#endif
}

// ---------------- dec_w (256 x 16384 fp32) -> dec_wT (16384 x 256 bf16) ----------------
__global__ __launch_bounds__(256) void k_transb(const float* __restrict__ dec_w,
                                                unsigned short* __restrict__ decT) {
  __shared__ float tile[32][33];
  int j0 = blockIdx.x * 32, o0 = blockIdx.y * 32;
  int tx = threadIdx.x & 31, ty = threadIdx.x >> 5;
#pragma unroll
  for (int rr = 0; rr < 4; rr++)
    tile[ty + rr * 8][tx] = dec_w[(size_t)(o0 + ty + rr * 8) * HID_DIM + (j0 + tx)];
  __syncthreads();
#pragma unroll
  for (int rr = 0; rr < 4; rr++)
    decT[(size_t)(j0 + ty + rr * 8) * OUT_DIM + (o0 + tx)] = f_to_bf16_rne(tile[tx][ty + rr * 8]);
}

// ---- blocked transpose: src[R x 256] -> dst[R/128][256][128] (values exact; layout only) ----
__global__ __launch_bounds__(256) void k_transblk(const float* __restrict__ src,
                                                  float* __restrict__ dst) {
  __shared__ float tile[32][33];
  const int r0 = blockIdx.x * 32, k0 = blockIdx.y * 32;
  const int tx = threadIdx.x & 31, ty = threadIdx.x >> 5;
#pragma unroll
  for (int rr = 0; rr < 4; rr++)
    tile[ty + rr * 8][tx] = src[(size_t)(r0 + ty + rr * 8) * IN_DIM + (k0 + tx)];
  __syncthreads();
  const int blk = r0 >> 7, rin = r0 & 127;
#pragma unroll
  for (int rr = 0; rr < 4; rr++) {
    const int kk = k0 + ty + rr * 8;
    dst[((size_t)blk * IN_DIM + kk) * 128 + rin + tx] = tile[tx][ty + rr * 8];
  }
}

// ---------------- GEMM1 (packed fp32, DMA staging): hid = relu(x @ enc_w^T + enc_b) ---------
// Per-element fp sequence BIT-IDENTICAL to R3/R6/R7: acc=0; ascending-k IEEE fma chain;
// h = acc + enc_b; relu. Inputs come from the blocked transposes (exact copies).
// FIX vs R8: global_load_lds global address must be PER-LANE (base + lane*16B); the LDS
// destination is the wave-uniform operand. R8 passed a uniform global pointer -> every
// lane fetched the same 16B.
__global__ __launch_bounds__(256, 4) void k_gemm_pk2(const float* __restrict__ XT,
                                                     const float* __restrict__ WT,
                                                     const float* __restrict__ encb,
                                                     float* __restrict__ hid) {
  __shared__ __align__(16) float As[32 * 128];   // [k][m], 16 KB
  __shared__ __align__(16) float Bs[32 * 128];   // [k][n]
  const int bn = blockIdx.x, bm = blockIdx.y;
  const int t = threadIdx.x, w = t >> 6, lane = t & 63;
  const int tx = t & 15, ty = t >> 4;            // 16x16 threads, 8x8 outputs each

  f32x2 acc[8][4] = {};                          // [i][j-pair]; col = tx*8 + jp*2 + {0,1}

  const float* Abase = XT + (size_t)bm * (IN_DIM * 128);
  const float* Bbase = WT + (size_t)bn * (IN_DIM * 128);

  for (int k0 = 0; k0 < IN_DIM; k0 += 32) {
    // Stage 16 KB per array: 16 wave-ops of 1 KB each; lane i moves bytes [i*16, i*16+16).
#pragma unroll
    for (int o = 0; o < 4; o++) {
      const int i = w * 4 + o;
      load_lds_16B(Abase + k0 * 128 + i * 256 + lane * 4, &As[i * 256]);
      load_lds_16B(Bbase + k0 * 128 + i * 256 + lane * 4, &Bs[i * 256]);
    }
    __syncthreads();
#pragma unroll 8
    for (int kk = 0; kk < 32; kk++) {            // ascending k: preserves fp order
      const f32x4 av0 = *(const f32x4*)&As[kk * 128 + ty * 8];
      const f32x4 av1 = *(const f32x4*)&As[kk * 128 + ty * 8 + 4];
      const f32x4 bv0 = *(const f32x4*)&Bs[kk * 128 + tx * 8];
      const f32x4 bv1 = *(const f32x4*)&Bs[kk * 128 + tx * 8 + 4];
      f32x2 b2[4];
      b2[0] = __builtin_shufflevector(bv0, bv0, 0, 1);
      b2[1] = __builtin_shufflevector(bv0, bv0, 2, 3);
      b2[2] = __builtin_shufflevector(bv1, bv1, 0, 1);
      b2[3] = __builtin_shufflevector(bv1, bv1, 2, 3);
#pragma unroll
      for (int i = 0; i < 8; i++) {
        const float asc = (i < 4) ? av0[i & 3] : av1[i & 3];
        f32x2 ai; ai[0] = asc; ai[1] = asc;
#pragma unroll
        for (int j = 0; j < 4; j++)
          acc[i][j] = fma2(ai, b2[j], acc[i][j]);
      }
    }
    __syncthreads();
  }

#pragma unroll
  for (int i = 0; i < 8; i++) {
    const int m = bm * 128 + ty * 8 + i;
    float o[8];
#pragma unroll
    for (int j = 0; j < 4; j++) {
      const float h0 = acc[i][j][0] + encb[bn * 128 + tx * 8 + j * 2];
      const float h1 = acc[i][j][1] + encb[bn * 128 + tx * 8 + j * 2 + 1];
      o[j * 2]     = (h0 > 0.f) ? h0 : 0.f;
      o[j * 2 + 1] = (h1 > 0.f) ? h1 : 0.f;
    }
    float* dst = &hid[(size_t)m * HID_DIM + bn * 128 + tx * 8];
    *(float4*)dst = *(float4*)&o[0];
    *(float4*)(dst + 4) = *(float4*)&o[4];
  }
}

// ---------------- topk5: byte-hist + compact + rank-select (R3/R6 selection semantics) --------
// T = exact bits of k-th largest stored value; keep iff bits >= T. 3 register scans total.
__global__ __launch_bounds__(256) void k_topk5(const unsigned short* __restrict__ decTb,
                                               const float* __restrict__ decb,
                                               const int* __restrict__ kptr,
                                               float* __restrict__ out,
                                               float* __restrict__ hid) {
  __shared__ unsigned hist[8][257];
  __shared__ unsigned cums[257];
  __shared__ unsigned candB[TKCAP];
  __shared__ float selV[SELCAPF];
  __shared__ unsigned short selI[SELCAPF];
  __shared__ unsigned s_selcnt, s_cnt, s_need, s_T, s_bin, s_B;
  __shared__ int s_keepall;

  const int r = blockIdx.x, t = threadIdx.x;
  float* hrow = hid + (size_t)r * HID_DIM;
  const int k = read_k(kptr);

  // Row -> registers (the ONLY global read of the row).
  f32x4 row[16];
#pragma unroll
  for (int c = 0; c < 16; c++) row[c] = *(const f32x4*)&hrow[(c * 256 + t) * 4];

  for (int i = t; i < 8 * 257; i += 256) ((unsigned*)hist)[i] = 0u;
  if (t == 0) { s_selcnt = 0; s_cnt = 0; s_keepall = 0; s_T = 0; }
  __syncthreads();

  // Scan 1: top-byte histogram (post-relu => sign 0); skip byte 0 (zeros).
#pragma unroll
  for (int c = 0; c < 16; c++)
#pragma unroll
    for (int e = 0; e < 4; e++) {
      const unsigned b = __float_as_uint(row[c][e]) >> 24;
      if (b) atomicAdd(&hist[t & 7][b], 1u);
    }
  __syncthreads();
  { unsigned s = 0;
#pragma unroll
    for (int cpy = 0; cpy < 8; cpy++) s += hist[cpy][t];
    cums[t] = s; }
  __syncthreads();
  for (int off = 1; off < 256; off <<= 1) {      // suffix scan: cums[t] = #{top-byte >= t}
    const unsigned v = cums[t];
    const unsigned a = (t + off < 256) ? cums[t + off] : 0u;
    __syncthreads();
    cums[t] = v + a;
    __syncthreads();
  }
  if (t == 0 && cums[1] < (unsigned)k) s_keepall = 1;   // k-th is (sub)zero -> keep all
  if (t >= 1) {
    const unsigned incl = cums[t], excl = (t < 255) ? cums[t + 1] : 0u;
    if (incl >= (unsigned)k && excl < (unsigned)k) { s_B = (unsigned)t; s_need = (unsigned)k - excl; }
  }
  __syncthreads();

  const int keepall = s_keepall;
  unsigned T = 0u;
  if (!keepall) {
    unsigned prefix = s_B;
    int shift = 24;
    // Scan 2: compact candidate bits matching the prefix; narrow 4 bits on cap overflow (rare).
    for (;;) {
      if (t == 0) s_cnt = 0;
      __syncthreads();
#pragma unroll
      for (int c = 0; c < 16; c++)
#pragma unroll
        for (int e = 0; e < 4; e++) {
          const unsigned bits = __float_as_uint(row[c][e]);
          if ((bits >> shift) == prefix) {
            const unsigned p = atomicAdd(&s_cnt, 1u);
            if (p < TKCAP) candB[p] = bits;
          }
        }
      __syncthreads();
      if (s_cnt <= TKCAP || shift == 0) break;
      const int nsh = shift - 4;
      if (t < 16) cums[t] = 0u;
      __syncthreads();
#pragma unroll
      for (int c = 0; c < 16; c++)
#pragma unroll
        for (int e = 0; e < 4; e++) {
          const unsigned bits = __float_as_uint(row[c][e]);
          if ((bits >> shift) == prefix) atomicAdd(&cums[(bits >> nsh) & 15u], 1u);
        }
      __syncthreads();
      if (t == 0) {
        unsigned cum = 0; const unsigned need = s_need;
        for (int b = 15; b >= 0; b--) {
          const unsigned c2 = cums[b];
          if (cum + c2 >= need) { s_bin = (unsigned)b; s_need = need - cum; break; }
          cum += c2;
        }
      }
      __syncthreads();
      prefix = (prefix << 4) | s_bin;
      shift = nsh;
      __syncthreads();
    }
    if (shift == 0 && s_cnt > TKCAP) {
      if (t == 0) s_T = prefix;                  // all candidates identical -> T determined
    } else {
      const unsigned n = s_cnt;                  // expected ~372; rank-select exact T
      const unsigned need = s_need;
      for (unsigned i = t; i < n; i += 256) {
        const unsigned v = candB[i];
        unsigned g = 0, e = 0;
        for (unsigned j = 0; j < n; j++) {
          const unsigned u = candB[j];
          g += (u > v); e += (u == v);
        }
        if (g < need && need <= g + e) s_T = v;  // unique value; any writer writes same bits
      }
    }
    __syncthreads();
    T = s_T;
  }

  // Scan 3: mask + write hidden_post + gather survivors (all from registers).
#pragma unroll
  for (int c = 0; c < 16; c++) {
    const int base = (c * 256 + t) * 4;
    f32x4 o;
#pragma unroll
    for (int e = 0; e < 4; e++) {
      const float v = row[c][e];
      const unsigned bits = __float_as_uint(v);
      const bool keep = keepall || (bits >= T);
      o[e] = keep ? v : 0.f;
      if (keep && bits != 0u) {
        const unsigned p = atomicAdd(&s_selcnt, 1u);
        if (p < SELCAPF) { selV[p] = v; selI[p] = (unsigned short)(base + e); }
      }
    }
    *(f32x4*)&hrow[base] = o;
  }
  __syncthreads();

  // Fused sparse decode, 8 accumulator chains for load pipelining.
  const unsigned nsel = s_selcnt;
  float a0 = decb[t], a1 = 0.f, a2 = 0.f, a3 = 0.f, a4 = 0.f, a5 = 0.f, a6 = 0.f, a7 = 0.f;
  if (nsel <= SELCAPF) {
    unsigned s = 0;
    for (; s + 8 <= nsel; s += 8) {
      a0 += selV[s + 0] * bf16u_to_f(decTb[(size_t)selI[s + 0] * OUT_DIM + t]);
      a1 += selV[s + 1] * bf16u_to_f(decTb[(size_t)selI[s + 1] * OUT_DIM + t]);
      a2 += selV[s + 2] * bf16u_to_f(decTb[(size_t)selI[s + 2] * OUT_DIM + t]);
      a3 += selV[s + 3] * bf16u_to_f(decTb[(size_t)selI[s + 3] * OUT_DIM + t]);
      a4 += selV[s + 4] * bf16u_to_f(decTb[(size_t)selI[s + 4] * OUT_DIM + t]);
      a5 += selV[s + 5] * bf16u_to_f(decTb[(size_t)selI[s + 5] * OUT_DIM + t]);
      a6 += selV[s + 6] * bf16u_to_f(decTb[(size_t)selI[s + 6] * OUT_DIM + t]);
      a7 += selV[s + 7] * bf16u_to_f(decTb[(size_t)selI[s + 7] * OUT_DIM + t]);
    }
    for (; s < nsel; s++)
      a0 += selV[s] * bf16u_to_f(decTb[(size_t)selI[s] * OUT_DIM + t]);
  } else {
    for (int j = 0; j < HID_DIM; j++) {          // rare huge-k fallback (row already masked)
      const float hv = hrow[j];
      if (hv != 0.f) a0 += hv * bf16u_to_f(decTb[(size_t)j * OUT_DIM + t]);
    }
  }
  out[(size_t)r * OUT_DIM + t] = (((a0 + a1) + (a2 + a3)) + ((a4 + a5) + (a6 + a7)));
}

// ======================= fallback (small ws): R7's proven kernels =======================
__global__ __launch_bounds__(256, 4) void k_gemm_pk(const float* __restrict__ X,
                                                    const float* __restrict__ W,
                                                    const float* __restrict__ encb,
                                                    float* __restrict__ hid) {
  __shared__ float As[32][132];
  __shared__ float Bs[32][132];
  const int bn = blockIdx.x, bm = blockIdx.y;
  const int t = threadIdx.x;
  const int tx = t & 15, ty = t >> 4;
  const int sr = t & 127, sh = t >> 7;
  f32x2 acc[8][4] = {};
  const float* Ab = X + (size_t)(bm * 128) * IN_DIM;
  const float* Bb = W + (size_t)(bn * 128) * IN_DIM;
  for (int k0 = 0; k0 < IN_DIM; k0 += 32) {
#pragma unroll
    for (int q = 0; q < 4; q++) {
      const int ko = sh * 16 + q * 4;
      const float4 av = *(const float4*)&Ab[(size_t)sr * IN_DIM + k0 + ko];
      As[ko + 0][sr] = av.x; As[ko + 1][sr] = av.y;
      As[ko + 2][sr] = av.z; As[ko + 3][sr] = av.w;
      const float4 bv = *(const float4*)&Bb[(size_t)sr * IN_DIM + k0 + ko];
      Bs[ko + 0][sr] = bv.x; Bs[ko + 1][sr] = bv.y;
      Bs[ko + 2][sr] = bv.z; Bs[ko + 3][sr] = bv.w;
    }
    __syncthreads();
#pragma unroll 8
    for (int kk = 0; kk < 32; kk++) {
      const f32x4 av0 = *(const f32x4*)&As[kk][ty * 8];
      const f32x4 av1 = *(const f32x4*)&As[kk][ty * 8 + 4];
      const f32x4 bv0 = *(const f32x4*)&Bs[kk][tx * 8];
      const f32x4 bv1 = *(const f32x4*)&Bs[kk][tx * 8 + 4];
      f32x2 b2[4];
      b2[0] = __builtin_shufflevector(bv0, bv0, 0, 1);
      b2[1] = __builtin_shufflevector(bv0, bv0, 2, 3);
      b2[2] = __builtin_shufflevector(bv1, bv1, 0, 1);
      b2[3] = __builtin_shufflevector(bv1, bv1, 2, 3);
#pragma unroll
      for (int i = 0; i < 8; i++) {
        const float asc = (i < 4) ? av0[i & 3] : av1[i & 3];
        f32x2 ai; ai[0] = asc; ai[1] = asc;
#pragma unroll
        for (int j = 0; j < 4; j++) acc[i][j] = fma2(ai, b2[j], acc[i][j]);
      }
    }
    __syncthreads();
  }
#pragma unroll
  for (int i = 0; i < 8; i++) {
    const int m = bm * 128 + ty * 8 + i;
    float o[8];
#pragma unroll
    for (int j = 0; j < 4; j++) {
      const float h0 = acc[i][j][0] + encb[bn * 128 + tx * 8 + j * 2];
      const float h1 = acc[i][j][1] + encb[bn * 128 + tx * 8 + j * 2 + 1];
      o[j * 2] = (h0 > 0.f) ? h0 : 0.f;
      o[j * 2 + 1] = (h1 > 0.f) ? h1 : 0.f;
    }
    float* dst = &hid[(size_t)m * HID_DIM + bn * 128 + tx * 8];
    *(float4*)dst = *(float4*)&o[0];
    *(float4*)(dst + 4) = *(float4*)&o[4];
  }
}

__global__ __launch_bounds__(256) void k_topkf(const float* __restrict__ dec,
                                               const float* __restrict__ decb,
                                               const int* __restrict__ kptr,
                                               float* __restrict__ out,
                                               float* __restrict__ hid) {
  __shared__ unsigned hist[8][257];
  __shared__ unsigned tot[256];
  __shared__ float selV[SELCAPF];
  __shared__ unsigned short selI[SELCAPF];
  __shared__ unsigned s_selcnt, s_need, s_pref, s_byte;
  __shared__ int s_keepall;
  const int r = blockIdx.x, t = threadIdx.x;
  float* hrow = hid + (size_t)r * HID_DIM;
  const int k = read_k(kptr);
  for (int i = t; i < 8 * 257; i += 256) ((unsigned*)hist)[i] = 0u;
  if (t == 0) { s_selcnt = 0; s_keepall = 0; s_pref = 0; }
  __syncthreads();
#pragma unroll
  for (int c = 0; c < 16; c++) {
    const f32x4 v = *(const f32x4*)&hrow[(c * 256 + t) * 4];
#pragma unroll
    for (int e = 0; e < 4; e++) {
      const unsigned b = __float_as_uint(v[e]) >> 24;
      if (b) atomicAdd(&hist[t & 7][b], 1u);
    }
  }
  __syncthreads();
  { unsigned s = 0;
#pragma unroll
    for (int c = 0; c < 8; c++) s += hist[c][t];
    tot[t] = s; }
  __syncthreads();
  if (t == 0) {
    unsigned cum = 0; int b1 = -1; unsigned need = 0;
    for (int b = 255; b >= 1; b--) {
      const unsigned c = tot[b];
      if (cum + c >= (unsigned)k) { b1 = b; need = (unsigned)k - cum; break; }
      cum += c;
    }
    if (b1 < 0) s_keepall = 1;
    else { s_pref = ((unsigned)b1) << 24; s_need = need; }
  }
  __syncthreads();
  if (!s_keepall) {
    for (int pass = 1; pass <= 3; pass++) {
      const int shift = 24 - pass * 8;
      tot[t] = 0;
      __syncthreads();
      const unsigned prefhi = s_pref >> (shift + 8);
#pragma unroll
      for (int c = 0; c < 16; c++) {
        const f32x4 v = *(const f32x4*)&hrow[(c * 256 + t) * 4];
#pragma unroll
        for (int e = 0; e < 4; e++) {
          const unsigned bits = __float_as_uint(v[e]);
          if ((bits >> (shift + 8)) == prefhi) atomicAdd(&tot[(bits >> shift) & 255u], 1u);
        }
      }
      __syncthreads();
      if (t == 0) {
        unsigned cum = 0; const unsigned need = s_need;
        for (int b = 255; b >= 0; b--) {
          const unsigned c = tot[b];
          if (cum + c >= need) { s_byte = (unsigned)b; s_need = need - cum; break; }
          cum += c;
        }
        s_pref |= s_byte << shift;
      }
      __syncthreads();
    }
  }
  const int keepall = s_keepall;
  const unsigned T = s_pref;
#pragma unroll
  for (int c = 0; c < 16; c++) {
    const int base = (c * 256 + t) * 4;
    const f32x4 v = *(const f32x4*)&hrow[base];
    f32x4 o;
#pragma unroll
    for (int e = 0; e < 4; e++) {
      const unsigned bits = __float_as_uint(v[e]);
      const bool keep = keepall || (bits >= T);
      o[e] = keep ? v[e] : 0.f;
      if (keep && bits != 0u) {
        const unsigned p = atomicAdd(&s_selcnt, 1u);
        if (p < SELCAPF) { selV[p] = v[e]; selI[p] = (unsigned short)(base + e); }
      }
    }
    *(f32x4*)&hrow[base] = o;
  }
  __syncthreads();
  const unsigned nsel = s_selcnt;
  float a0 = decb[t], a1 = 0.f, a2 = 0.f, a3 = 0.f;
  if (nsel <= SELCAPF) {
    unsigned s = 0;
    for (; s + 4 <= nsel; s += 4) {
#pragma unroll
      for (int u = 0; u < 4; u++) {
        const unsigned idx = selI[s + u];
        (u == 0 ? a0 : u == 1 ? a1 : u == 2 ? a2 : a3) += selV[s + u] * dec[(size_t)t * HID_DIM + idx];
      }
    }
    for (; s < nsel; s++)
      a0 += selV[s] * dec[(size_t)t * HID_DIM + selI[s]];
  } else {
    for (int j = 0; j < HID_DIM; j++) {
      const float hv = hrow[j];
      if (hv != 0.f) a0 += hv * dec[(size_t)t * HID_DIM + j];
    }
  }
  out[(size_t)r * OUT_DIM + t] = (a0 + a1) + (a2 + a3);
}

extern "C" void kernel_launch(void* const* d_in, const int* in_sizes, int n_in,
                              void* d_out, int out_size, void* d_ws, size_t ws_size,
                              hipStream_t stream) {
  // Order remap (dict vs alphabetical), by size signature — proven in R3-R7.
  int ix = 0, iew = 1, ieb = 2, idw = 3, idb = 4, ik = 5;
  if (n_in >= 6 && in_sizes[0] == OUT_DIM && in_sizes[5] == BATCH * IN_DIM) {
    idb = 0; idw = 1; ieb = 2; iew = 3; ik = 4; ix = 5;
  }
  const float* x     = (const float*)d_in[ix];
  const float* enc_w = (const float*)d_in[iew];
  const float* enc_b = (const float*)d_in[ieb];
  const float* dec_w = (const float*)d_in[idw];
  const float* dec_b = (const float*)d_in[idb];
  const int*   kptr  = (const int*)d_in[ik];

  float* out = (float*)d_out;
  float* hid = out + (size_t)BATCH * OUT_DIM;

  const size_t B_decT = (size_t)HID_DIM * OUT_DIM * 2;   // 8 MiB
  const size_t B_XT   = (size_t)BATCH * IN_DIM * 4;      // 8 MiB
  const size_t B_WT   = (size_t)HID_DIM * IN_DIM * 4;    // 16 MiB
  const size_t need = 64 + B_decT + B_XT + B_WT;         // 32 MiB + 64 (proven available R4/R5)

  if (ws_size >= need) {
    unsigned char* p = (unsigned char*)d_ws;
    unsigned short* decTb = (unsigned short*)(p + 64);
    float* XT = (float*)(p + 64 + B_decT);
    float* WT = (float*)(p + 64 + B_decT + B_XT);
    k_transblk<<<dim3(BATCH / 32, IN_DIM / 32), 256, 0, stream>>>(x, XT);
    k_transblk<<<dim3(HID_DIM / 32, IN_DIM / 32), 256, 0, stream>>>(enc_w, WT);
    k_transb<<<dim3(HID_DIM / 32, OUT_DIM / 32), 256, 0, stream>>>(dec_w, decTb);
    k_gemm_pk2<<<dim3(HID_DIM / 128, BATCH / 128), 256, 0, stream>>>(XT, WT, enc_b, hid);
    k_topk5<<<dim3(BATCH), 256, 0, stream>>>(decTb, dec_b, kptr, out, hid);
  } else {
    k_gemm_pk<<<dim3(HID_DIM / 128, BATCH / 128), 256, 0, stream>>>(x, enc_w, enc_b, hid);
    k_topkf<<<dim3(BATCH), 256, 0, stream>>>(dec_w, dec_b, kptr, out, hid);
  }
}

// Round 10
// 1498.084 us; speedup vs baseline: 1.1461x; 1.1461x over previous
//
#include <hip/hip_runtime.h>
#include <stdint.h>

#define BATCH   8192
#define IN_DIM  256
#define HID_DIM 16384
#define OUT_DIM 256

#define SELCAPF 2048

typedef __attribute__((ext_vector_type(4))) float f32x4;
typedef __attribute__((ext_vector_type(2))) float f32x2;

__device__ __forceinline__ void load_lds_16B(const void* g, void* l) {
  __builtin_amdgcn_global_load_lds(
      (const __attribute__((address_space(1))) unsigned int*)g,
      (__attribute__((address_space(3))) unsigned int*)l, 16, 0, 0);
}
__device__ __forceinline__ float bf16u_to_f(unsigned short u) {
  return __uint_as_float(((unsigned)u) << 16);
}
__device__ __forceinline__ unsigned short f_to_bf16_rne(float f) {
  unsigned u = __float_as_uint(f);
  u += 0x7fffu + ((u >> 16) & 1u);
  return (unsigned short)(u >> 16);
}
__device__ __forceinline__ int read_k(const int* kptr) {
  int k = kptr[0];
  if (k <= 0 || k > 100000000) {
    float kf = __int_as_float(k);
    if (kf >= 1.f && kf <= 16384.f) k = (int)kf;
  }
  if (k < 1) k = 1;
  if (k > HID_DIM) k = HID_DIM;
  return k;
}
__device__ __forceinline__ f32x2 fma2(f32x2 a, f32x2 b, f32x2 c) {
#if __has_builtin(__builtin_elementwise_fma)
  return __builtin_elementwise_fma(a, b, c);   // v_pk_fma_f32: two independent IEEE FMAs
#else
  f32x2 r; r[0] = fmaf(a[0], b[0], c[0]); r[1] = fmaf(a[1], b[1], c[1]); return r;
#endif
}

// ---------------- dec_w (256 x 16384 fp32) -> dec_wT (16384 x 256 bf16) ----------------
__global__ __launch_bounds__(256) void k_transb(const float* __restrict__ dec_w,
                                                unsigned short* __restrict__ decT) {
  __shared__ float tile[32][33];
  int j0 = blockIdx.x * 32, o0 = blockIdx.y * 32;
  int tx = threadIdx.x & 31, ty = threadIdx.x >> 5;
#pragma unroll
  for (int rr = 0; rr < 4; rr++)
    tile[ty + rr * 8][tx] = dec_w[(size_t)(o0 + ty + rr * 8) * HID_DIM + (j0 + tx)];
  __syncthreads();
#pragma unroll
  for (int rr = 0; rr < 4; rr++)
    decT[(size_t)(j0 + ty + rr * 8) * OUT_DIM + (o0 + tx)] = f_to_bf16_rne(tile[tx][ty + rr * 8]);
}

// ---- blocked transpose: src[R x 256] -> dst[R/128][256][128] (values exact; layout only) ----
__global__ __launch_bounds__(256) void k_transblk(const float* __restrict__ src,
                                                  float* __restrict__ dst) {
  __shared__ float tile[32][33];
  const int r0 = blockIdx.x * 32, k0 = blockIdx.y * 32;
  const int tx = threadIdx.x & 31, ty = threadIdx.x >> 5;
#pragma unroll
  for (int rr = 0; rr < 4; rr++)
    tile[ty + rr * 8][tx] = src[(size_t)(r0 + ty + rr * 8) * IN_DIM + (k0 + tx)];
  __syncthreads();
  const int blk = r0 >> 7, rin = r0 & 127;
#pragma unroll
  for (int rr = 0; rr < 4; rr++) {
    const int kk = k0 + ty + rr * 8;
    dst[((size_t)blk * IN_DIM + kk) * 128 + rin + tx] = tile[tx][ty + rr * 8];
  }
}

// ---------------- GEMM1 (packed fp32, DMA staging): hid = relu(x @ enc_w^T + enc_b) ---------
// Per-element fp sequence BIT-IDENTICAL to R3/R6/R7/R9: acc=0; ascending-k IEEE fma chain;
// h = acc + enc_b; relu. Proven at 764 us in R9 (unchanged here).
__global__ __launch_bounds__(256, 4) void k_gemm_pk2(const float* __restrict__ XT,
                                                     const float* __restrict__ WT,
                                                     const float* __restrict__ encb,
                                                     float* __restrict__ hid) {
  __shared__ __align__(16) float As[32 * 128];   // [k][m], 16 KB
  __shared__ __align__(16) float Bs[32 * 128];   // [k][n]
  const int bn = blockIdx.x, bm = blockIdx.y;
  const int t = threadIdx.x, w = t >> 6, lane = t & 63;
  const int tx = t & 15, ty = t >> 4;            // 16x16 threads, 8x8 outputs each

  f32x2 acc[8][4] = {};                          // [i][j-pair]; col = tx*8 + jp*2 + {0,1}

  const float* Abase = XT + (size_t)bm * (IN_DIM * 128);
  const float* Bbase = WT + (size_t)bn * (IN_DIM * 128);

  for (int k0 = 0; k0 < IN_DIM; k0 += 32) {
    // Stage 16 KB per array: 16 wave-ops of 1 KB each; lane i moves bytes [i*16, i*16+16).
#pragma unroll
    for (int o = 0; o < 4; o++) {
      const int i = w * 4 + o;
      load_lds_16B(Abase + k0 * 128 + i * 256 + lane * 4, &As[i * 256]);
      load_lds_16B(Bbase + k0 * 128 + i * 256 + lane * 4, &Bs[i * 256]);
    }
    __syncthreads();
#pragma unroll 8
    for (int kk = 0; kk < 32; kk++) {            // ascending k: preserves fp order
      const f32x4 av0 = *(const f32x4*)&As[kk * 128 + ty * 8];
      const f32x4 av1 = *(const f32x4*)&As[kk * 128 + ty * 8 + 4];
      const f32x4 bv0 = *(const f32x4*)&Bs[kk * 128 + tx * 8];
      const f32x4 bv1 = *(const f32x4*)&Bs[kk * 128 + tx * 8 + 4];
      f32x2 b2[4];
      b2[0] = __builtin_shufflevector(bv0, bv0, 0, 1);
      b2[1] = __builtin_shufflevector(bv0, bv0, 2, 3);
      b2[2] = __builtin_shufflevector(bv1, bv1, 0, 1);
      b2[3] = __builtin_shufflevector(bv1, bv1, 2, 3);
#pragma unroll
      for (int i = 0; i < 8; i++) {
        const float asc = (i < 4) ? av0[i & 3] : av1[i & 3];
        f32x2 ai; ai[0] = asc; ai[1] = asc;
#pragma unroll
        for (int j = 0; j < 4; j++)
          acc[i][j] = fma2(ai, b2[j], acc[i][j]);
      }
    }
    __syncthreads();
  }

#pragma unroll
  for (int i = 0; i < 8; i++) {
    const int m = bm * 128 + ty * 8 + i;
    float o[8];
#pragma unroll
    for (int j = 0; j < 4; j++) {
      const float h0 = acc[i][j][0] + encb[bn * 128 + tx * 8 + j * 2];
      const float h1 = acc[i][j][1] + encb[bn * 128 + tx * 8 + j * 2 + 1];
      o[j * 2]     = (h0 > 0.f) ? h0 : 0.f;
      o[j * 2 + 1] = (h1 > 0.f) ? h1 : 0.f;
    }
    float* dst = &hid[(size_t)m * HID_DIM + bn * 128 + tx * 8];
    *(float4*)dst = *(float4*)&o[0];
    *(float4*)(dst + 4) = *(float4*)&o[4];
  }
}

// ---------------- topk3 (R6 verbatim, proven): reg-resident row, full 32-bit radix, fused decode
// Selection rule: T = exact bits of k-th largest stored value; keep iff bits >= T.
__global__ __launch_bounds__(256) void k_topk3(const unsigned short* __restrict__ decTb,
                                               const float* __restrict__ decb,
                                               const int* __restrict__ kptr,
                                               float* __restrict__ out,
                                               float* __restrict__ hid) {
  __shared__ unsigned hist[8][257];
  __shared__ unsigned cums[257];
  __shared__ float selV[SELCAPF];
  __shared__ unsigned short selI[SELCAPF];
  __shared__ unsigned s_selcnt, s_b, s_need;
  __shared__ int s_keepall;

  const int r = blockIdx.x, t = threadIdx.x;
  float* hrow = hid + (size_t)r * HID_DIM;
  const int k = read_k(kptr);

  // Row -> registers (the ONLY global read of the row).
  f32x4 row[16];
#pragma unroll
  for (int c = 0; c < 16; c++) row[c] = *(const f32x4*)&hrow[(c * 256 + t) * 4];

  for (int i = t; i < 8 * 257; i += 256) ((unsigned*)hist)[i] = 0u;
  if (t == 0) { s_selcnt = 0; s_keepall = 0; }
  __syncthreads();

  // Radix pass 0: top byte (post-relu => sign bit 0); skip byte==0.
#pragma unroll
  for (int c = 0; c < 16; c++)
#pragma unroll
    for (int e = 0; e < 4; e++) {
      const unsigned b = __float_as_uint(row[c][e]) >> 24;
      if (b) atomicAdd(&hist[t & 7][b], 1u);
    }
  __syncthreads();
  { unsigned s = 0;
#pragma unroll
    for (int cpy = 0; cpy < 8; cpy++) s += hist[cpy][t];
    cums[t] = s; }
  __syncthreads();
  for (int off = 1; off < 256; off <<= 1) {   // suffix scan: cums[t] = #{top-byte >= t}
    const unsigned v = cums[t];
    const unsigned a = (t + off < 256) ? cums[t + off] : 0u;
    __syncthreads();
    cums[t] = v + a;
    __syncthreads();
  }
  if (t == 0 && cums[1] < (unsigned)k) s_keepall = 1;  // k-th is (sub)zero -> keep all
  if (t >= 1) {
    const unsigned incl = cums[t], excl = (t < 255) ? cums[t + 1] : 0u;
    if (incl >= (unsigned)k && excl < (unsigned)k) { s_b = (unsigned)t; s_need = (unsigned)k - excl; }
  }
  __syncthreads();

  unsigned prefix = 0;
  const int keepall = s_keepall;
  if (!keepall) {
    prefix = s_b << 24;
    unsigned need = s_need;
    for (int pass = 0; pass < 3; pass++) {     // shifts 16, 8, 0 -> full 32-bit T
      const int shift = 16 - pass * 8;
      for (int i = t; i < 8 * 257; i += 256) ((unsigned*)hist)[i] = 0u;
      __syncthreads();
      const unsigned pfx = prefix;
      const int pshift = shift + 8;
#pragma unroll
      for (int c = 0; c < 16; c++)
#pragma unroll
        for (int e = 0; e < 4; e++) {
          const unsigned bits = __float_as_uint(row[c][e]);
          if ((bits >> pshift) == (pfx >> pshift))
            atomicAdd(&hist[t & 7][(bits >> shift) & 255u], 1u);
        }
      __syncthreads();
      { unsigned s = 0;
#pragma unroll
        for (int cpy = 0; cpy < 8; cpy++) s += hist[cpy][t];
        cums[t] = s; }
      __syncthreads();
      for (int off = 1; off < 256; off <<= 1) {
        const unsigned v = cums[t];
        const unsigned a = (t + off < 256) ? cums[t + off] : 0u;
        __syncthreads();
        cums[t] = v + a;
        __syncthreads();
      }
      { const unsigned incl = cums[t], excl = (t < 255) ? cums[t + 1] : 0u;
        if (incl >= need && excl < need) { s_b = (unsigned)t; s_need = need - excl; } }
      __syncthreads();
      prefix |= s_b << shift;
      need = s_need;
      __syncthreads();
    }
  }
  const unsigned T = prefix;   // exact bits of the k-th largest value (ties kept via >=)

  // Mask + write hidden_post + gather survivors (all from registers).
#pragma unroll
  for (int c = 0; c < 16; c++) {
    const int base = (c * 256 + t) * 4;
    f32x4 o;
#pragma unroll
    for (int e = 0; e < 4; e++) {
      const float v = row[c][e];
      const unsigned bits = __float_as_uint(v);
      const bool keep = keepall || (bits >= T);
      o[e] = keep ? v : 0.f;
      if (keep && bits != 0u) {
        const unsigned p = atomicAdd(&s_selcnt, 1u);
        if (p < SELCAPF) { selV[p] = v; selI[p] = (unsigned short)(base + e); }
      }
    }
    *(f32x4*)&hrow[base] = o;
  }
  __syncthreads();

  // Fused sparse decode: out[r][t] = dec_b[t] + sum_s v_s * dec_w[t][j_s]
  const unsigned nsel = s_selcnt;
  float a0 = decb[t], a1 = 0.f, a2 = 0.f, a3 = 0.f;
  if (nsel <= SELCAPF) {
    unsigned s = 0;
    for (; s + 4 <= nsel; s += 4) {
      a0 += selV[s + 0] * bf16u_to_f(decTb[(size_t)selI[s + 0] * OUT_DIM + t]);
      a1 += selV[s + 1] * bf16u_to_f(decTb[(size_t)selI[s + 1] * OUT_DIM + t]);
      a2 += selV[s + 2] * bf16u_to_f(decTb[(size_t)selI[s + 2] * OUT_DIM + t]);
      a3 += selV[s + 3] * bf16u_to_f(decTb[(size_t)selI[s + 3] * OUT_DIM + t]);
    }
    for (; s < nsel; s++)
      a0 += selV[s] * bf16u_to_f(decTb[(size_t)selI[s] * OUT_DIM + t]);
  } else {
    for (int j = 0; j < HID_DIM; j++) {        // rare huge-k fallback (row already masked)
      const float hv = hrow[j];
      if (hv != 0.f) a0 += hv * bf16u_to_f(decTb[(size_t)j * OUT_DIM + t]);
    }
  }
  out[(size_t)r * OUT_DIM + t] = (a0 + a1) + (a2 + a3);
}

// ======================= fallback (small ws): R7's proven kernels =======================
__global__ __launch_bounds__(256, 4) void k_gemm_pk(const float* __restrict__ X,
                                                    const float* __restrict__ W,
                                                    const float* __restrict__ encb,
                                                    float* __restrict__ hid) {
  __shared__ float As[32][132];
  __shared__ float Bs[32][132];
  const int bn = blockIdx.x, bm = blockIdx.y;
  const int t = threadIdx.x;
  const int tx = t & 15, ty = t >> 4;
  const int sr = t & 127, sh = t >> 7;
  f32x2 acc[8][4] = {};
  const float* Ab = X + (size_t)(bm * 128) * IN_DIM;
  const float* Bb = W + (size_t)(bn * 128) * IN_DIM;
  for (int k0 = 0; k0 < IN_DIM; k0 += 32) {
#pragma unroll
    for (int q = 0; q < 4; q++) {
      const int ko = sh * 16 + q * 4;
      const float4 av = *(const float4*)&Ab[(size_t)sr * IN_DIM + k0 + ko];
      As[ko + 0][sr] = av.x; As[ko + 1][sr] = av.y;
      As[ko + 2][sr] = av.z; As[ko + 3][sr] = av.w;
      const float4 bv = *(const float4*)&Bb[(size_t)sr * IN_DIM + k0 + ko];
      Bs[ko + 0][sr] = bv.x; Bs[ko + 1][sr] = bv.y;
      Bs[ko + 2][sr] = bv.z; Bs[ko + 3][sr] = bv.w;
    }
    __syncthreads();
#pragma unroll 8
    for (int kk = 0; kk < 32; kk++) {
      const f32x4 av0 = *(const f32x4*)&As[kk][ty * 8];
      const f32x4 av1 = *(const f32x4*)&As[kk][ty * 8 + 4];
      const f32x4 bv0 = *(const f32x4*)&Bs[kk][tx * 8];
      const f32x4 bv1 = *(const f32x4*)&Bs[kk][tx * 8 + 4];
      f32x2 b2[4];
      b2[0] = __builtin_shufflevector(bv0, bv0, 0, 1);
      b2[1] = __builtin_shufflevector(bv0, bv0, 2, 3);
      b2[2] = __builtin_shufflevector(bv1, bv1, 0, 1);
      b2[3] = __builtin_shufflevector(bv1, bv1, 2, 3);
#pragma unroll
      for (int i = 0; i < 8; i++) {
        const float asc = (i < 4) ? av0[i & 3] : av1[i & 3];
        f32x2 ai; ai[0] = asc; ai[1] = asc;
#pragma unroll
        for (int j = 0; j < 4; j++) acc[i][j] = fma2(ai, b2[j], acc[i][j]);
      }
    }
    __syncthreads();
  }
#pragma unroll
  for (int i = 0; i < 8; i++) {
    const int m = bm * 128 + ty * 8 + i;
    float o[8];
#pragma unroll
    for (int j = 0; j < 4; j++) {
      const float h0 = acc[i][j][0] + encb[bn * 128 + tx * 8 + j * 2];
      const float h1 = acc[i][j][1] + encb[bn * 128 + tx * 8 + j * 2 + 1];
      o[j * 2] = (h0 > 0.f) ? h0 : 0.f;
      o[j * 2 + 1] = (h1 > 0.f) ? h1 : 0.f;
    }
    float* dst = &hid[(size_t)m * HID_DIM + bn * 128 + tx * 8];
    *(float4*)dst = *(float4*)&o[0];
    *(float4*)(dst + 4) = *(float4*)&o[4];
  }
}

__global__ __launch_bounds__(256) void k_topkf(const float* __restrict__ dec,
                                               const float* __restrict__ decb,
                                               const int* __restrict__ kptr,
                                               float* __restrict__ out,
                                               float* __restrict__ hid) {
  __shared__ unsigned hist[8][257];
  __shared__ unsigned tot[256];
  __shared__ float selV[SELCAPF];
  __shared__ unsigned short selI[SELCAPF];
  __shared__ unsigned s_selcnt, s_need, s_pref, s_byte;
  __shared__ int s_keepall;
  const int r = blockIdx.x, t = threadIdx.x;
  float* hrow = hid + (size_t)r * HID_DIM;
  const int k = read_k(kptr);
  for (int i = t; i < 8 * 257; i += 256) ((unsigned*)hist)[i] = 0u;
  if (t == 0) { s_selcnt = 0; s_keepall = 0; s_pref = 0; }
  __syncthreads();
#pragma unroll
  for (int c = 0; c < 16; c++) {
    const f32x4 v = *(const f32x4*)&hrow[(c * 256 + t) * 4];
#pragma unroll
    for (int e = 0; e < 4; e++) {
      const unsigned b = __float_as_uint(v[e]) >> 24;
      if (b) atomicAdd(&hist[t & 7][b], 1u);
    }
  }
  __syncthreads();
  { unsigned s = 0;
#pragma unroll
    for (int c = 0; c < 8; c++) s += hist[c][t];
    tot[t] = s; }
  __syncthreads();
  if (t == 0) {
    unsigned cum = 0; int b1 = -1; unsigned need = 0;
    for (int b = 255; b >= 1; b--) {
      const unsigned c = tot[b];
      if (cum + c >= (unsigned)k) { b1 = b; need = (unsigned)k - cum; break; }
      cum += c;
    }
    if (b1 < 0) s_keepall = 1;
    else { s_pref = ((unsigned)b1) << 24; s_need = need; }
  }
  __syncthreads();
  if (!s_keepall) {
    for (int pass = 1; pass <= 3; pass++) {
      const int shift = 24 - pass * 8;
      tot[t] = 0;
      __syncthreads();
      const unsigned prefhi = s_pref >> (shift + 8);
#pragma unroll
      for (int c = 0; c < 16; c++) {
        const f32x4 v = *(const f32x4*)&hrow[(c * 256 + t) * 4];
#pragma unroll
        for (int e = 0; e < 4; e++) {
          const unsigned bits = __float_as_uint(v[e]);
          if ((bits >> (shift + 8)) == prefhi) atomicAdd(&tot[(bits >> shift) & 255u], 1u);
        }
      }
      __syncthreads();
      if (t == 0) {
        unsigned cum = 0; const unsigned need = s_need;
        for (int b = 255; b >= 0; b--) {
          const unsigned c = tot[b];
          if (cum + c >= need) { s_byte = (unsigned)b; s_need = need - cum; break; }
          cum += c;
        }
        s_pref |= s_byte << shift;
      }
      __syncthreads();
    }
  }
  const int keepall = s_keepall;
  const unsigned T = s_pref;
#pragma unroll
  for (int c = 0; c < 16; c++) {
    const int base = (c * 256 + t) * 4;
    const f32x4 v = *(const f32x4*)&hrow[base];
    f32x4 o;
#pragma unroll
    for (int e = 0; e < 4; e++) {
      const unsigned bits = __float_as_uint(v[e]);
      const bool keep = keepall || (bits >= T);
      o[e] = keep ? v[e] : 0.f;
      if (keep && bits != 0u) {
        const unsigned p = atomicAdd(&s_selcnt, 1u);
        if (p < SELCAPF) { selV[p] = v[e]; selI[p] = (unsigned short)(base + e); }
      }
    }
    *(f32x4*)&hrow[base] = o;
  }
  __syncthreads();
  const unsigned nsel = s_selcnt;
  float a0 = decb[t], a1 = 0.f, a2 = 0.f, a3 = 0.f;
  if (nsel <= SELCAPF) {
    unsigned s = 0;
    for (; s + 4 <= nsel; s += 4) {
#pragma unroll
      for (int u = 0; u < 4; u++) {
        const unsigned idx = selI[s + u];
        (u == 0 ? a0 : u == 1 ? a1 : u == 2 ? a2 : a3) += selV[s + u] * dec[(size_t)t * HID_DIM + idx];
      }
    }
    for (; s < nsel; s++)
      a0 += selV[s] * dec[(size_t)t * HID_DIM + selI[s]];
  } else {
    for (int j = 0; j < HID_DIM; j++) {
      const float hv = hrow[j];
      if (hv != 0.f) a0 += hv * dec[(size_t)t * HID_DIM + j];
    }
  }
  out[(size_t)r * OUT_DIM + t] = (a0 + a1) + (a2 + a3);
}

extern "C" void kernel_launch(void* const* d_in, const int* in_sizes, int n_in,
                              void* d_out, int out_size, void* d_ws, size_t ws_size,
                              hipStream_t stream) {
  // Order remap (dict vs alphabetical), by size signature — proven in R3-R9.
  int ix = 0, iew = 1, ieb = 2, idw = 3, idb = 4, ik = 5;
  if (n_in >= 6 && in_sizes[0] == OUT_DIM && in_sizes[5] == BATCH * IN_DIM) {
    idb = 0; idw = 1; ieb = 2; iew = 3; ik = 4; ix = 5;
  }
  const float* x     = (const float*)d_in[ix];
  const float* enc_w = (const float*)d_in[iew];
  const float* enc_b = (const float*)d_in[ieb];
  const float* dec_w = (const float*)d_in[idw];
  const float* dec_b = (const float*)d_in[idb];
  const int*   kptr  = (const int*)d_in[ik];

  float* out = (float*)d_out;
  float* hid = out + (size_t)BATCH * OUT_DIM;

  const size_t B_decT = (size_t)HID_DIM * OUT_DIM * 2;   // 8 MiB
  const size_t B_XT   = (size_t)BATCH * IN_DIM * 4;      // 8 MiB
  const size_t B_WT   = (size_t)HID_DIM * IN_DIM * 4;    // 16 MiB
  const size_t need = 64 + B_decT + B_XT + B_WT;         // 32 MiB + 64 (proven available)

  if (ws_size >= need) {
    unsigned char* p = (unsigned char*)d_ws;
    unsigned short* decTb = (unsigned short*)(p + 64);
    float* XT = (float*)(p + 64 + B_decT);
    float* WT = (float*)(p + 64 + B_decT + B_XT);
    k_transblk<<<dim3(BATCH / 32, IN_DIM / 32), 256, 0, stream>>>(x, XT);
    k_transblk<<<dim3(HID_DIM / 32, IN_DIM / 32), 256, 0, stream>>>(enc_w, WT);
    k_transb<<<dim3(HID_DIM / 32, OUT_DIM / 32), 256, 0, stream>>>(dec_w, decTb);
    k_gemm_pk2<<<dim3(HID_DIM / 128, BATCH / 128), 256, 0, stream>>>(XT, WT, enc_b, hid);
    k_topk3<<<dim3(BATCH), 256, 0, stream>>>(decTb, dec_b, kptr, out, hid);
  } else {
    k_gemm_pk<<<dim3(HID_DIM / 128, BATCH / 128), 256, 0, stream>>>(x, enc_w, enc_b, hid);
    k_topkf<<<dim3(BATCH), 256, 0, stream>>>(dec_w, dec_b, kptr, out, hid);
  }
}